// Round 9
// baseline (101.905 us; speedup 1.0000x reference)
//
#include <hip/hip_runtime.h>
#include <math.h>

#define NB 8
#define H 64
#define W 64
#define C 128
#define G 8
#define GC 16
#define P 9
#define NPIX (NB * H * W)     // 32768
#define N_OFF 144
#define N_MSK 72
#define PXB 32
#define RECW 232              // record row stride in u16 (464 B)
#define PK_IN_ELEMS   (8 * 4 * 64 * 8)    // 16384
#define PK_COMB_ELEMS (14 * 4 * 64 * 8)   // 28672
#define PK_OUT_ELEMS  (8 * 4 * 64 * 8)    // 16384

using bf16x8 = __attribute__((ext_vector_type(8))) short;
using f32x4  = __attribute__((ext_vector_type(4))) float;
using u32x4  = __attribute__((ext_vector_type(4))) unsigned;

__device__ __forceinline__ short f2bf(float f) {
    union { float fv; unsigned u; } v; v.fv = f;
    unsigned r = v.u + 0x7fffu + ((v.u >> 16) & 1u);
    return (short)(r >> 16);
}

// ---------------- K0: pack weights into MFMA B-fragment order, bf16 --------
__global__ __launch_bounds__(256) void k_pack(
    const float* __restrict__ w_in, const float* __restrict__ w_off,
    const float* __restrict__ w_msk, const float* __restrict__ w_out,
    short* __restrict__ pk_in, short* __restrict__ pk_comb, short* __restrict__ pk_out)
{
    const int tid = blockIdx.x * 256 + threadIdx.x;
    int p, which;
    if (tid < PK_IN_ELEMS) { p = tid; which = 0; }
    else if (tid < PK_IN_ELEMS + PK_COMB_ELEMS) { p = tid - PK_IN_ELEMS; which = 1; }
    else if (tid < PK_IN_ELEMS + PK_COMB_ELEMS + PK_OUT_ELEMS) { p = tid - PK_IN_ELEMS - PK_COMB_ELEMS; which = 2; }
    else return;
    const int e = p & 7, lane = (p >> 3) & 63, kt = (p >> 9) & 3, nt = p >> 11;
    const int k = kt * 32 + (lane >> 4) * 8 + e;
    const int n = nt * 16 + (lane & 15);
    float v;
    if (which == 0) {
        v = w_in[k * C + n];
        pk_in[p] = f2bf(v);
    } else if (which == 1) {
        if (n < N_OFF) v = w_off[k * N_OFF + n];
        else if (n < N_OFF + N_MSK) v = w_msk[k * N_MSK + (n - N_OFF)];
        else v = 0.f;
        pk_comb[p] = f2bf(v);
    } else {
        v = w_out[k * C + n];
        pk_out[p] = f2bf(v);
    }
}

// ---- K_fm: dwconv+LN+GELU + inproj MFMA -> xproj planar ----
// ----       + offset/mask MFMA + softmax -> 448B/px records in out slots ---
__global__ __launch_bounds__(256, 2) void k_fm(
    const float* __restrict__ x, const float* __restrict__ dw_w,
    const float* __restrict__ dw_b, const float* __restrict__ ln_g,
    const float* __restrict__ ln_b, const short* __restrict__ pk_in,
    const float* __restrict__ b_in, const short* __restrict__ pk_comb,
    const float* __restrict__ b_off, const float* __restrict__ b_msk,
    unsigned short* __restrict__ xproj, float* __restrict__ out)
{
    __shared__ __align__(16) short xa[PXB * C];
    __shared__ __align__(16) short x1s[PXB * C];
    __shared__ unsigned short recs[PXB * RECW];
    __shared__ float part[PXB][8][2];
    __shared__ float stats[PXB][2];

    const int t = threadIdx.x;
    const int n = blockIdx.x & 7;
    const int local = blockIdx.x >> 3;
    const int y = local >> 1;
    const int xb = (local & 1) * PXB;
    const int gpix0 = (n * H + y) * W + xb;

    const int px = t >> 3;
    const int c8 = t & 7;
    const int c0 = c8 * 16;
    const int gpx = gpix0 + px;

    float a[16];
    #pragma unroll
    for (int q = 0; q < 4; ++q) {
        f32x4 v = *(const f32x4*)(dw_b + c0 + q * 4);
        #pragma unroll
        for (int e = 0; e < 4; ++e) a[q * 4 + e] = v[e];
    }
    #pragma unroll
    for (int ky = 0; ky < 3; ++ky) {
        const int yy = y + ky - 1;
        if (yy < 0 || yy >= H) continue;
        #pragma unroll
        for (int kx = 0; kx < 3; ++kx) {
            const int xx = xb + px + kx - 1;
            if (xx < 0 || xx >= W) continue;
            const float* xp = x + ((size_t)(n * H + yy) * W + xx) * C + c0;
            const float* wp = dw_w + (ky * 3 + kx) * C + c0;
            #pragma unroll
            for (int q = 0; q < 4; ++q) {
                f32x4 xv = *(const f32x4*)(xp + q * 4);
                f32x4 wv = *(const f32x4*)(wp + q * 4);
                #pragma unroll
                for (int e = 0; e < 4; ++e)
                    a[q * 4 + e] = fmaf(xv[e], wv[e], a[q * 4 + e]);
            }
        }
    }
    {
        const float* cp = x + (size_t)gpx * C + c0;
        const int sw = (px & 7) << 4;
        #pragma unroll
        for (int h = 0; h < 2; ++h) {
            f32x4 v0 = *(const f32x4*)(cp + h * 8);
            f32x4 v1 = *(const f32x4*)(cp + h * 8 + 4);
            bf16x8 pk;
            #pragma unroll
            for (int e = 0; e < 4; ++e) { pk[e] = f2bf(v0[e]); pk[4 + e] = f2bf(v1[e]); }
            *(bf16x8*)((char*)xa + px * 256 + ((c8 * 32 + h * 16) ^ sw)) = pk;
        }
    }
    {
        float s = 0.f, sq = 0.f;
        #pragma unroll
        for (int cc = 0; cc < 16; ++cc) { s += a[cc]; sq = fmaf(a[cc], a[cc], sq); }
        part[px][c8][0] = s;
        part[px][c8][1] = sq;
    }
    __syncthreads();
    if (t < PXB) {
        float S = 0.f, Q = 0.f;
        #pragma unroll
        for (int q = 0; q < 8; ++q) { S += part[t][q][0]; Q += part[t][q][1]; }
        const float mu = S * (1.f / C);
        const float va = Q * (1.f / C) - mu * mu;
        stats[t][0] = mu;
        stats[t][1] = rsqrtf(va + 1e-6f);
    }
    __syncthreads();
    {
        const float mu = stats[px][0], rs = stats[px][1];
        const int sw = (px & 7) << 4;
        #pragma unroll
        for (int h = 0; h < 2; ++h) {
            bf16x8 pk;
            #pragma unroll
            for (int e = 0; e < 8; ++e) {
                const int cc = h * 8 + e;
                float v = (a[cc] - mu) * rs * ln_g[c0 + cc] + ln_b[c0 + cc];
                pk[e] = f2bf(v * 0.5f * (1.f + erff(v * 0.70710678118654752f)));
            }
            *(bf16x8*)((char*)x1s + px * 256 + ((c8 * 32 + h * 16) ^ sw)) = pk;
        }
    }
    __syncthreads();

    {
        const int w = t >> 6, l = t & 63;
        const int swA = (l & 7) << 4;
        bf16x8 aA[2][4], aB[2][4];
        #pragma unroll
        for (int mt = 0; mt < 2; ++mt) {
            const int m = mt * 16 + (l & 15);
            #pragma unroll
            for (int kt = 0; kt < 4; ++kt) {
                const int byte = m * 256 + ((kt * 64 + (l >> 4) * 16) ^ swA);
                aA[mt][kt] = *(const bf16x8*)((char*)xa + byte);
                aB[mt][kt] = *(const bf16x8*)((char*)x1s + byte);
            }
        }
        #pragma unroll
        for (int i = 0; i < 2; ++i) {
            const int nt = w + i * 4;
            bf16x8 bf[4];
            const short* bp = pk_in + nt * 2048 + l * 8;
            #pragma unroll
            for (int kt = 0; kt < 4; ++kt) bf[kt] = *(const bf16x8*)(bp + kt * 512);
            const float bias = b_in[nt * 16 + (l & 15)];
            #pragma unroll
            for (int mt = 0; mt < 2; ++mt) {
                f32x4 acc = {0.f, 0.f, 0.f, 0.f};
                #pragma unroll
                for (int kt = 0; kt < 4; ++kt)
                    acc = __builtin_amdgcn_mfma_f32_16x16x32_bf16(aA[mt][kt], bf[kt], acc, 0, 0, 0);
                const int prow = gpix0 + mt * 16 + (l >> 4) * 4;
                #pragma unroll
                for (int r = 0; r < 4; ++r)
                    xproj[(size_t)(nt * NPIX + prow + r) * 16 + (l & 15)] =
                        (unsigned short)f2bf(acc[r] + bias);
            }
        }
        #pragma unroll
        for (int i = 0; i < 4; ++i) {
            const int nt = w + i * 4;
            if (nt < 14) {
                bf16x8 bf[4];
                const short* bp = pk_comb + nt * 2048 + l * 8;
                #pragma unroll
                for (int kt = 0; kt < 4; ++kt) bf[kt] = *(const bf16x8*)(bp + kt * 512);
                const int col = nt * 16 + (l & 15);
                int dcol = col;
                float bias = 0.f;
                bool valid = true;
                if (col < N_OFF) bias = b_off[col];
                else {
                    const int cm = col - N_OFF;
                    if (cm < N_MSK) {
                        const int g = (cm * 57) >> 9;
                        dcol = 144 + g * 10 + (cm - 9 * g);
                        bias = b_msk[cm];
                    } else valid = false;
                }
                #pragma unroll
                for (int mt = 0; mt < 2; ++mt) {
                    f32x4 acc = {0.f, 0.f, 0.f, 0.f};
                    #pragma unroll
                    for (int kt = 0; kt < 4; ++kt)
                        acc = __builtin_amdgcn_mfma_f32_16x16x32_bf16(aB[mt][kt], bf[kt], acc, 0, 0, 0);
                    if (valid) {
                        const int pr0 = mt * 16 + (l >> 4) * 4;
                        #pragma unroll
                        for (int r = 0; r < 4; ++r)
                            recs[(pr0 + r) * RECW + dcol] = (unsigned short)f2bf(acc[r] + bias);
                    }
                }
            }
        }
    }
    __syncthreads();

    {
        const int spx = t >> 3, g = t & 7;
        unsigned short* row = recs + spx * RECW + 144 + g * 10;
        float lg[P];
        #pragma unroll
        for (int p = 0; p < P; ++p) lg[p] = __uint_as_float(((unsigned)row[p]) << 16);
        float mx = lg[0];
        #pragma unroll
        for (int p2 = 1; p2 < P; ++p2) mx = fmaxf(mx, lg[p2]);
        float e[P], s = 0.f;
        #pragma unroll
        for (int p2 = 0; p2 < P; ++p2) { e[p2] = expf(lg[p2] - mx); s += e[p2]; }
        const float inv = 1.0f / s;
        #pragma unroll
        for (int p2 = 0; p2 < P; ++p2) row[p2] = (unsigned short)f2bf(e[p2] * inv);
    }
    __syncthreads();

    {
        const int spx = t >> 3, q0 = t & 7;
        const char* srcL = (const char*)recs + spx * (RECW * 2);
        char* dst = (char*)out + (size_t)(gpix0 + spx) * 512;
        #pragma unroll
        for (int h = 0; h < 4; ++h) {
            const int q = q0 + h * 8;
            if (q < 28)
                *(bf16x8*)(dst + q * 16) = *(const bf16x8*)(srcL + q * 16);
        }
    }
}

// ---- K_samp: LDS-windowed deformable gather + output projection ----
// block = 32 px; loop over 4 group-pairs, staging a 5-row x 40-col window.
__global__ __launch_bounds__(256, 2) void k_samp(
    const unsigned short* __restrict__ xproj, const short* __restrict__ pk_out,
    const float* __restrict__ b_out, float* __restrict__ out)
{
    __shared__ __align__(16) short smp[PXB * C];          // 8 KB sampled bf16
    __shared__ unsigned short recsS[PXB * RECW];          // 14.5 KB records
    __shared__ __align__(16) unsigned win[3200];          // 12.8 KB window (2 groups)

    const int t = threadIdx.x;
    const int n = blockIdx.x & 7;
    const int local = blockIdx.x >> 3;
    const int y = local >> 1;
    const int xb = (local & 1) * PXB;
    const int gpix0 = (n * H + y) * W + xb;
    const int imgbase = n * (H * W);

    // ---- stage records (coalesced) ----
    {
        const int spx = t >> 3, q0 = t & 7;
        const char* src = (const char*)out + (size_t)(gpix0 + spx) * 512;
        char* dstL = (char*)recsS + spx * (RECW * 2);
        #pragma unroll
        for (int h = 0; h < 4; ++h) {
            const int q = q0 + h * 8;
            if (q < 28)
                *(bf16x8*)(dstL + q * 16) = *(const bf16x8*)(src + q * 16);
        }
    }

    const int px = t & 31;            // sampling thread mapping
    const int g2 = (t >> 5) & 1;
    const int cq = t >> 6;            // channel quad 0..3
    const int sw = (px & 7) << 4;

    for (int gi = 0; gi < 4; ++gi) {
        __syncthreads();              // records ready (iter 0) / prev sampling done
        // ---- stage 5x40 window for groups (2gi, 2gi+1), bf16 ----
        for (int u = t; u < 1600; u += 256) {
            const int ucq = u & 3;
            const int v = u >> 2;            // 0..399
            const int xs = v % 40;
            const int v2 = v / 40;           // 0..9
            const int rs = v2 % 5;
            const int ug2 = v2 / 5;
            const int g = gi * 2 + ug2;
            const int row = min(max(y - 2 + rs, 0), H - 1);
            const int col = min(max(xb - 4 + xs, 0), W - 1);
            const unsigned long long val = *(const unsigned long long*)
                (xproj + ((size_t)(g * NPIX + imgbase + row * W + col)) * 16 + ucq * 4);
            *(unsigned long long*)((char*)win + ug2 * 6400 +
                                   (((ucq * 5 + rs) * 40 + xs) << 3)) = val;
        }
        __syncthreads();

        // ---- sample: thread = (px, g2, cq) -> 4 channels of (px, g) ----
        {
            const int g = gi * 2 + g2;
            const unsigned* rec32 = (const unsigned*)recsS + px * (RECW / 2);
            const unsigned short* prp = recsS + px * RECW + 144 + g * 10;
            const unsigned short* plane = xproj + (size_t)(g * NPIX + imgbase) * 16;
            const char* wbase = (const char*)win + g2 * 6400 + cq * 1600;
            float acc4[4] = {0.f, 0.f, 0.f, 0.f};
            #pragma unroll
            for (int p = 0; p < P; ++p) {
                const unsigned ov = rec32[g * 9 + p];
                const float offx = __uint_as_float(ov << 16);
                const float offy = __uint_as_float(ov & 0xffff0000u);
                const float mk = __uint_as_float(((unsigned)prp[p]) << 16);
                const float ux = (float)(xb + px + (p / 3) - 1) + offx;
                const float uy = (float)(y + (p % 3) - 1) + offy;
                const float fx = floorf(ux), fy = floorf(uy);
                const float wx = ux - fx, wy = uy - fy;
                const int x0 = (int)fx, y0 = (int)fy;
                float w00 = mk * (1.f - wx) * (1.f - wy);
                float w10 = mk * wx * (1.f - wy);
                float w01 = mk * (1.f - wx) * wy;
                float w11 = mk * wx * wy;
                if (!((x0 >= 0) & (x0 < W)))       { w00 = 0.f; w01 = 0.f; }
                if (!((x0 >= -1) & (x0 < W - 1)))  { w10 = 0.f; w11 = 0.f; }
                if (!((y0 >= 0) & (y0 < H)))       { w00 = 0.f; w10 = 0.f; }
                if (!((y0 >= -1) & (y0 < H - 1)))  { w01 = 0.f; w11 = 0.f; }
                const int x0c = min(max(x0, 0), W - 1), x1c = min(max(x0 + 1, 0), W - 1);
                const int y0c = min(max(y0, 0), H - 1), y1c = min(max(y0 + 1, 0), H - 1);
                const int sy0 = y0c - y + 2, sy1 = y1c - y + 2;
                const int sx0 = x0c - xb + 4, sx1 = x1c - xb + 4;
                const bool iy0 = ((unsigned)sy0 <= 4u), iy1 = ((unsigned)sy1 <= 4u);
                const bool ix0 = ((unsigned)sx0 <= 39u), ix1 = ((unsigned)sx1 <= 39u);
                #pragma unroll
                for (int cnr = 0; cnr < 4; ++cnr) {
                    const float wgt = (cnr == 0) ? w00 : (cnr == 1) ? w10
                                    : (cnr == 2) ? w01 : w11;
                    const int cx = (cnr & 1) ? x1c : x0c;
                    const int cy = (cnr & 2) ? y1c : y0c;
                    const int sx = (cnr & 1) ? sx1 : sx0;
                    const int sy = (cnr & 2) ? sy1 : sy0;
                    const bool inw = ((cnr & 1) ? ix1 : ix0) & ((cnr & 2) ? iy1 : iy0);
                    unsigned long long vv = 0;
                    if (wgt != 0.f) {
                        if (inw)
                            vv = *(const unsigned long long*)(wbase + ((sy * 40 + sx) << 3));
                        else
                            vv = *(const unsigned long long*)
                                 (plane + (size_t)(cy * W + cx) * 16 + cq * 4);
                    }
                    const unsigned u0 = (unsigned)vv, u1 = (unsigned)(vv >> 32);
                    acc4[0] = fmaf(wgt, __uint_as_float(u0 << 16), acc4[0]);
                    acc4[1] = fmaf(wgt, __uint_as_float(u0 & 0xffff0000u), acc4[1]);
                    acc4[2] = fmaf(wgt, __uint_as_float(u1 << 16), acc4[2]);
                    acc4[3] = fmaf(wgt, __uint_as_float(u1 & 0xffff0000u), acc4[3]);
                }
            }
            // write 4 ch -> smp (bf16, swizzled), 8-B store
            const unsigned lo = ((unsigned)(unsigned short)f2bf(acc4[0])) |
                                (((unsigned)(unsigned short)f2bf(acc4[1])) << 16);
            const unsigned hi = ((unsigned)(unsigned short)f2bf(acc4[2])) |
                                (((unsigned)(unsigned short)f2bf(acc4[3])) << 16);
            unsigned long long packed = ((unsigned long long)hi << 32) | lo;
            *(unsigned long long*)((char*)smp + px * 256 + ((g * 32 + cq * 8) ^ sw)) = packed;
        }
    }
    __syncthreads();

    // ---- output projection via MFMA (nt-partitioned) ----
    {
        const int w = t >> 6, l = t & 63;
        const int swA = (l & 7) << 4;
        bf16x8 aS[2][4];
        #pragma unroll
        for (int mt = 0; mt < 2; ++mt) {
            const int m = mt * 16 + (l & 15);
            #pragma unroll
            for (int kt = 0; kt < 4; ++kt)
                aS[mt][kt] = *(const bf16x8*)((char*)smp + m * 256 +
                                              ((kt * 64 + (l >> 4) * 16) ^ swA));
        }
        #pragma unroll
        for (int i = 0; i < 2; ++i) {
            const int nt = w + i * 4;
            bf16x8 bf[4];
            const short* bp = pk_out + nt * 2048 + l * 8;
            #pragma unroll
            for (int kt = 0; kt < 4; ++kt) bf[kt] = *(const bf16x8*)(bp + kt * 512);
            const float bias = b_out[nt * 16 + (l & 15)];
            #pragma unroll
            for (int mt = 0; mt < 2; ++mt) {
                f32x4 acc = {0.f, 0.f, 0.f, 0.f};
                #pragma unroll
                for (int kt = 0; kt < 4; ++kt)
                    acc = __builtin_amdgcn_mfma_f32_16x16x32_bf16(aS[mt][kt], bf[kt], acc, 0, 0, 0);
                const int row0 = gpix0 + mt * 16 + (l >> 4) * 4;
                #pragma unroll
                for (int r = 0; r < 4; ++r)
                    out[(size_t)(row0 + r) * C + nt * 16 + (l & 15)] = acc[r] + bias;
            }
        }
    }
}

extern "C" void kernel_launch(void* const* d_in, const int* in_sizes, int n_in,
                              void* d_out, int out_size, void* d_ws, size_t ws_size,
                              hipStream_t stream)
{
    const float* x     = (const float*)d_in[0];
    const float* w_in  = (const float*)d_in[1];
    const float* b_in  = (const float*)d_in[2];
    const float* dw_w  = (const float*)d_in[3];
    const float* dw_b  = (const float*)d_in[4];
    const float* ln_g  = (const float*)d_in[5];
    const float* ln_b  = (const float*)d_in[6];
    const float* w_off = (const float*)d_in[7];
    const float* b_off = (const float*)d_in[8];
    const float* w_msk = (const float*)d_in[9];
    const float* b_msk = (const float*)d_in[10];
    const float* w_out = (const float*)d_in[11];
    const float* b_out = (const float*)d_in[12];

    short* pk_in   = (short*)d_ws;
    short* pk_comb = pk_in + PK_IN_ELEMS;
    short* pk_out  = pk_comb + PK_COMB_ELEMS;
    unsigned short* xproj = (unsigned short*)(pk_out + PK_OUT_ELEMS);  // 8.4 MB planar bf16
    float* out     = (float*)d_out;

    hipLaunchKernelGGL(k_pack, dim3(240), dim3(256), 0, stream,
                       w_in, w_off, w_msk, w_out, pk_in, pk_comb, pk_out);
    hipLaunchKernelGGL(k_fm, dim3(NPIX / PXB), dim3(256), 0, stream,
                       x, dw_w, dw_b, ln_g, ln_b, pk_in, b_in,
                       pk_comb, b_off, b_msk, xproj, out);
    hipLaunchKernelGGL(k_samp, dim3(NPIX / PXB), dim3(256), 0, stream,
                       xproj, pk_out, b_out, out);
}

// Round 10
// 79.600 us; speedup vs baseline: 1.2802x; 1.2802x over previous
//
#include <hip/hip_runtime.h>
#include <math.h>

#define NB 8
#define H 64
#define W 64
#define C 128
#define G 8
#define GC 16
#define P 9
#define NPIX (NB * H * W)     // 32768
#define N_OFF 144
#define N_MSK 72
#define PXB 32
#define RECW 232              // record row stride in u16 (464 B)
#define PK_IN_ELEMS   (8 * 4 * 64 * 8)    // 16384
#define PK_COMB_ELEMS (14 * 4 * 64 * 8)   // 28672
#define PK_OUT_ELEMS  (8 * 4 * 64 * 8)    // 16384

using bf16x8 = __attribute__((ext_vector_type(8))) short;
using f32x4  = __attribute__((ext_vector_type(4))) float;
using u32x4  = __attribute__((ext_vector_type(4))) unsigned;

__device__ __forceinline__ short f2bf(float f) {
    union { float fv; unsigned u; } v; v.fv = f;
    unsigned r = v.u + 0x7fffu + ((v.u >> 16) & 1u);
    return (short)(r >> 16);
}
__device__ __forceinline__ unsigned short f2h(float f) {
    _Float16 h = (_Float16)f;
    unsigned short u;
    __builtin_memcpy(&u, &h, 2);
    return u;
}
__device__ __forceinline__ float h2f(unsigned short u) {
    _Float16 h;
    __builtin_memcpy(&h, &u, 2);
    return (float)h;
}

// ---------------- K0: pack weights into MFMA B-fragment order, bf16 --------
__global__ __launch_bounds__(256) void k_pack(
    const float* __restrict__ w_in, const float* __restrict__ w_off,
    const float* __restrict__ w_msk, const float* __restrict__ w_out,
    short* __restrict__ pk_in, short* __restrict__ pk_comb, short* __restrict__ pk_out)
{
    const int tid = blockIdx.x * 256 + threadIdx.x;
    int p, which;
    if (tid < PK_IN_ELEMS) { p = tid; which = 0; }
    else if (tid < PK_IN_ELEMS + PK_COMB_ELEMS) { p = tid - PK_IN_ELEMS; which = 1; }
    else if (tid < PK_IN_ELEMS + PK_COMB_ELEMS + PK_OUT_ELEMS) { p = tid - PK_IN_ELEMS - PK_COMB_ELEMS; which = 2; }
    else return;
    const int e = p & 7, lane = (p >> 3) & 63, kt = (p >> 9) & 3, nt = p >> 11;
    const int k = kt * 32 + (lane >> 4) * 8 + e;
    const int n = nt * 16 + (lane & 15);
    float v;
    if (which == 0) {
        v = w_in[k * C + n];
        pk_in[p] = f2bf(v);
    } else if (which == 1) {
        if (n < N_OFF) v = w_off[k * N_OFF + n];
        else if (n < N_OFF + N_MSK) v = w_msk[k * N_MSK + (n - N_OFF)];
        else v = 0.f;
        pk_comb[p] = f2bf(v);
    } else {
        v = w_out[k * C + n];
        pk_out[p] = f2bf(v);
    }
}

// ---- K_fm: dwconv+LN+GELU + inproj MFMA -> xproj planar ----
// ----       + offset/mask MFMA + softmax -> 448B/px records in out slots ---
__global__ __launch_bounds__(256, 2) void k_fm(
    const float* __restrict__ x, const float* __restrict__ dw_w,
    const float* __restrict__ dw_b, const float* __restrict__ ln_g,
    const float* __restrict__ ln_b, const short* __restrict__ pk_in,
    const float* __restrict__ b_in, const short* __restrict__ pk_comb,
    const float* __restrict__ b_off, const float* __restrict__ b_msk,
    unsigned short* __restrict__ xproj, float* __restrict__ out)
{
    __shared__ __align__(16) short xa[PXB * C];
    __shared__ __align__(16) short x1s[PXB * C];
    __shared__ unsigned short recs[PXB * RECW];
    __shared__ float part[PXB][8][2];
    __shared__ float stats[PXB][2];

    const int t = threadIdx.x;
    const int n = blockIdx.x & 7;
    const int local = blockIdx.x >> 3;
    const int y = local >> 1;
    const int xb = (local & 1) * PXB;
    const int gpix0 = (n * H + y) * W + xb;

    const int px = t >> 3;
    const int c8 = t & 7;
    const int c0 = c8 * 16;
    const int gpx = gpix0 + px;

    float a[16];
    #pragma unroll
    for (int q = 0; q < 4; ++q) {
        f32x4 v = *(const f32x4*)(dw_b + c0 + q * 4);
        #pragma unroll
        for (int e = 0; e < 4; ++e) a[q * 4 + e] = v[e];
    }
    #pragma unroll
    for (int ky = 0; ky < 3; ++ky) {
        const int yy = y + ky - 1;
        if (yy < 0 || yy >= H) continue;
        #pragma unroll
        for (int kx = 0; kx < 3; ++kx) {
            const int xx = xb + px + kx - 1;
            if (xx < 0 || xx >= W) continue;
            const float* xp = x + ((size_t)(n * H + yy) * W + xx) * C + c0;
            const float* wp = dw_w + (ky * 3 + kx) * C + c0;
            #pragma unroll
            for (int q = 0; q < 4; ++q) {
                f32x4 xv = *(const f32x4*)(xp + q * 4);
                f32x4 wv = *(const f32x4*)(wp + q * 4);
                #pragma unroll
                for (int e = 0; e < 4; ++e)
                    a[q * 4 + e] = fmaf(xv[e], wv[e], a[q * 4 + e]);
            }
        }
    }
    {
        const float* cp = x + (size_t)gpx * C + c0;
        const int sw = (px & 7) << 4;
        #pragma unroll
        for (int h = 0; h < 2; ++h) {
            f32x4 v0 = *(const f32x4*)(cp + h * 8);
            f32x4 v1 = *(const f32x4*)(cp + h * 8 + 4);
            bf16x8 pk;
            #pragma unroll
            for (int e = 0; e < 4; ++e) { pk[e] = f2bf(v0[e]); pk[4 + e] = f2bf(v1[e]); }
            *(bf16x8*)((char*)xa + px * 256 + ((c8 * 32 + h * 16) ^ sw)) = pk;
        }
    }
    {
        float s = 0.f, sq = 0.f;
        #pragma unroll
        for (int cc = 0; cc < 16; ++cc) { s += a[cc]; sq = fmaf(a[cc], a[cc], sq); }
        part[px][c8][0] = s;
        part[px][c8][1] = sq;
    }
    __syncthreads();
    if (t < PXB) {
        float S = 0.f, Q = 0.f;
        #pragma unroll
        for (int q = 0; q < 8; ++q) { S += part[t][q][0]; Q += part[t][q][1]; }
        const float mu = S * (1.f / C);
        const float va = Q * (1.f / C) - mu * mu;
        stats[t][0] = mu;
        stats[t][1] = rsqrtf(va + 1e-6f);
    }
    __syncthreads();
    {
        const float mu = stats[px][0], rs = stats[px][1];
        const int sw = (px & 7) << 4;
        #pragma unroll
        for (int h = 0; h < 2; ++h) {
            bf16x8 pk;
            #pragma unroll
            for (int e = 0; e < 8; ++e) {
                const int cc = h * 8 + e;
                float v = (a[cc] - mu) * rs * ln_g[c0 + cc] + ln_b[c0 + cc];
                pk[e] = f2bf(v * 0.5f * (1.f + erff(v * 0.70710678118654752f)));
            }
            *(bf16x8*)((char*)x1s + px * 256 + ((c8 * 32 + h * 16) ^ sw)) = pk;
        }
    }
    __syncthreads();

    {
        const int w = t >> 6, l = t & 63;
        const int swA = (l & 7) << 4;
        bf16x8 aA[2][4], aB[2][4];
        #pragma unroll
        for (int mt = 0; mt < 2; ++mt) {
            const int m = mt * 16 + (l & 15);
            #pragma unroll
            for (int kt = 0; kt < 4; ++kt) {
                const int byte = m * 256 + ((kt * 64 + (l >> 4) * 16) ^ swA);
                aA[mt][kt] = *(const bf16x8*)((char*)xa + byte);
                aB[mt][kt] = *(const bf16x8*)((char*)x1s + byte);
            }
        }
        #pragma unroll
        for (int i = 0; i < 2; ++i) {
            const int nt = w + i * 4;
            bf16x8 bf[4];
            const short* bp = pk_in + nt * 2048 + l * 8;
            #pragma unroll
            for (int kt = 0; kt < 4; ++kt) bf[kt] = *(const bf16x8*)(bp + kt * 512);
            const float bias = b_in[nt * 16 + (l & 15)];
            #pragma unroll
            for (int mt = 0; mt < 2; ++mt) {
                f32x4 acc = {0.f, 0.f, 0.f, 0.f};
                #pragma unroll
                for (int kt = 0; kt < 4; ++kt)
                    acc = __builtin_amdgcn_mfma_f32_16x16x32_bf16(aA[mt][kt], bf[kt], acc, 0, 0, 0);
                const int prow = gpix0 + mt * 16 + (l >> 4) * 4;
                #pragma unroll
                for (int r = 0; r < 4; ++r)
                    xproj[(size_t)(nt * NPIX + prow + r) * 16 + (l & 15)] =
                        (unsigned short)f2bf(acc[r] + bias);
            }
        }
        #pragma unroll
        for (int i = 0; i < 4; ++i) {
            const int nt = w + i * 4;
            if (nt < 14) {
                bf16x8 bf[4];
                const short* bp = pk_comb + nt * 2048 + l * 8;
                #pragma unroll
                for (int kt = 0; kt < 4; ++kt) bf[kt] = *(const bf16x8*)(bp + kt * 512);
                const int col = nt * 16 + (l & 15);
                int dcol = col;
                float bias = 0.f;
                bool valid = true;
                if (col < N_OFF) bias = b_off[col];
                else {
                    const int cm = col - N_OFF;
                    if (cm < N_MSK) {
                        const int g = (cm * 57) >> 9;
                        dcol = 144 + g * 10 + (cm - 9 * g);
                        bias = b_msk[cm];
                    } else valid = false;
                }
                #pragma unroll
                for (int mt = 0; mt < 2; ++mt) {
                    f32x4 acc = {0.f, 0.f, 0.f, 0.f};
                    #pragma unroll
                    for (int kt = 0; kt < 4; ++kt)
                        acc = __builtin_amdgcn_mfma_f32_16x16x32_bf16(aB[mt][kt], bf[kt], acc, 0, 0, 0);
                    if (valid) {
                        const int pr0 = mt * 16 + (l >> 4) * 4;
                        #pragma unroll
                        for (int r = 0; r < 4; ++r)
                            recs[(pr0 + r) * RECW + dcol] = (unsigned short)f2bf(acc[r] + bias);
                    }
                }
            }
        }
    }
    __syncthreads();

    {
        const int spx = t >> 3, g = t & 7;
        unsigned short* row = recs + spx * RECW + 144 + g * 10;
        float lg[P];
        #pragma unroll
        for (int p = 0; p < P; ++p) lg[p] = __uint_as_float(((unsigned)row[p]) << 16);
        float mx = lg[0];
        #pragma unroll
        for (int p2 = 1; p2 < P; ++p2) mx = fmaxf(mx, lg[p2]);
        float e[P], s = 0.f;
        #pragma unroll
        for (int p2 = 0; p2 < P; ++p2) { e[p2] = expf(lg[p2] - mx); s += e[p2]; }
        const float inv = 1.0f / s;
        #pragma unroll
        for (int p2 = 0; p2 < P; ++p2) row[p2] = (unsigned short)f2bf(e[p2] * inv);
    }
    __syncthreads();

    {
        const int spx = t >> 3, q0 = t & 7;
        const char* srcL = (const char*)recs + spx * (RECW * 2);
        char* dst = (char*)out + (size_t)(gpix0 + spx) * 512;
        #pragma unroll
        for (int h = 0; h < 4; ++h) {
            const int q = q0 + h * 8;
            if (q < 28)
                *(bf16x8*)(dst + q * 16) = *(const bf16x8*)(srcL + q * 16);
        }
    }
}

// ---- K_samp: tap pre-pass + LDS-windowed gather (b128 taps) + out-proj ----
#define PADPX 33
#define PADX 41
__global__ __launch_bounds__(256, 2) void k_samp(
    const unsigned short* __restrict__ xproj, const short* __restrict__ pk_out,
    const float* __restrict__ b_out, float* __restrict__ out)
{
    __shared__ __align__(16) short smp[PXB * C];                 // 8 KB
    __shared__ unsigned long long taps_w[G * P * PADPX];         // 19 KB f16x4 weights
    __shared__ unsigned taps_i[G * P * PADPX];                   // 9.5 KB packed coords
    __shared__ __align__(16) u32x4 win[2 * 4 * 5 * PADX];        // 26.2 KB window

    const int t = threadIdx.x;
    const int n = blockIdx.x & 7;
    const int local = blockIdx.x >> 3;
    const int y = local >> 1;
    const int xb = (local & 1) * PXB;
    const int gpix0 = (n * H + y) * W + xb;
    const int imgbase = n * (H * W);

    // ---- phase 1: tap pre-pass, thread = (px, g) ----
    {
        const int px = t & 31, g = t >> 5;
        const unsigned* slot = (const unsigned*)((const char*)out +
                               (size_t)(gpix0 + px) * 512);
        unsigned ov[P];
        {
            u32x4 a0 = *(const u32x4*)(slot + g * 9);
            u32x4 a1 = *(const u32x4*)(slot + g * 9 + 4);
            ov[0]=a0[0]; ov[1]=a0[1]; ov[2]=a0[2]; ov[3]=a0[3];
            ov[4]=a1[0]; ov[5]=a1[1]; ov[6]=a1[2]; ov[7]=a1[3];
            ov[8] = slot[g * 9 + 8];
        }
        float pr[P];
        {
            u32x4 b0 = *(const u32x4*)(slot + 72 + 5 * g);
            #pragma unroll
            for (int i = 0; i < 4; ++i) {
                pr[2 * i] = __uint_as_float(b0[i] << 16);
                pr[2 * i + 1] = __uint_as_float(b0[i] & 0xffff0000u);
            }
            pr[8] = __uint_as_float(slot[72 + 5 * g + 4] << 16);
        }
        #pragma unroll
        for (int p = 0; p < P; ++p) {
            const float offx = __uint_as_float(ov[p] << 16);
            const float offy = __uint_as_float(ov[p] & 0xffff0000u);
            const float mk = pr[p];
            const float ux = (float)(xb + px + (p / 3) - 1) + offx;
            const float uy = (float)(y + (p % 3) - 1) + offy;
            const float fx = floorf(ux), fy = floorf(uy);
            const float wx = ux - fx, wy = uy - fy;
            const int x0 = (int)fx, y0 = (int)fy;
            float w00 = mk * (1.f - wx) * (1.f - wy);
            float w10 = mk * wx * (1.f - wy);
            float w01 = mk * (1.f - wx) * wy;
            float w11 = mk * wx * wy;
            if (!((x0 >= 0) & (x0 < W)))       { w00 = 0.f; w01 = 0.f; }
            if (!((x0 >= -1) & (x0 < W - 1)))  { w10 = 0.f; w11 = 0.f; }
            if (!((y0 >= 0) & (y0 < H)))       { w00 = 0.f; w10 = 0.f; }
            if (!((y0 >= -1) & (y0 < H - 1)))  { w01 = 0.f; w11 = 0.f; }
            const int x0c = min(max(x0, 0), W - 1), x1c = min(max(x0 + 1, 0), W - 1);
            const int y0c = min(max(y0, 0), H - 1), y1c = min(max(y0 + 1, 0), H - 1);
            const int sx0 = x0c - xb + 4, sx1 = x1c - xb + 4;   // [-28, 67]
            const int sy0 = y0c - y + 2,  sy1 = y1c - y + 2;    // [-61, 65]
            const unsigned long long tw =
                  (unsigned long long)f2h(w00)
                | ((unsigned long long)f2h(w10) << 16)
                | ((unsigned long long)f2h(w01) << 32)
                | ((unsigned long long)f2h(w11) << 48);
            const unsigned ti = (unsigned)(sx0 + 64)
                              | ((unsigned)(sy0 + 62) << 8)
                              | ((unsigned)(sx1 + 64) << 15)
                              | ((unsigned)(sy1 + 62) << 23);
            const int ti_idx = (g * P + p) * PADPX + px;
            taps_w[ti_idx] = tw;
            taps_i[ti_idx] = ti;
        }
    }

    // ---- phase 2/3: two window fills (groups 0-3, 4-7) + sampling ----
    const int spx = t & 31;
    const int gl = (t >> 5) & 3;
    const int half = t >> 7;
    const int swz = (spx & 7) << 4;

    #pragma unroll
    for (int f = 0; f < 2; ++f) {
        __syncthreads();   // taps ready (f=0) / prev sampling done (f=1)
        // stage window: 4 groups x 5 rows x 40 cols x 32B = 25.6 KB
        for (int k = 0; k < 7; ++k) {
            const int u = k * 256 + t;
            if (u < 1600) {
                const int uh = u & 1;
                const int v = u >> 1;           // 0..799
                const int xs = v % 40;
                const int w2 = v / 40;          // 0..19
                const int rs = w2 % 5;
                const int gs = w2 / 5;          // 0..3
                const int row = min(max(y - 2 + rs, 0), H - 1);
                const int col = min(max(xb - 4 + xs, 0), W - 1);
                win[((uh * 4 + gs) * 5 + rs) * PADX + xs] =
                    *(const u32x4*)(xproj +
                        ((size_t)((f * 4 + gs) * NPIX + imgbase + row * W + col)) * 16 + uh * 8);
            }
        }
        __syncthreads();

        // sample: thread = (spx, gl, half) -> 8 channels of group f*4+gl
        {
            const int g = f * 4 + gl;
            const u32x4* plane4 = (const u32x4*)(xproj + (size_t)(g * NPIX + imgbase) * 16);
            const u32x4* wb = win + (half * 4 + gl) * 5 * PADX;
            float acc[8];
            #pragma unroll
            for (int q = 0; q < 8; ++q) acc[q] = 0.f;
            #pragma unroll
            for (int p = 0; p < P; ++p) {
                const int ti_idx = (g * P + p) * PADPX + spx;
                const unsigned long long tw = taps_w[ti_idx];
                const unsigned ti = taps_i[ti_idx];
                const int sx0 = (int)(ti & 255u) - 64;
                const int sy0 = (int)((ti >> 8) & 127u) - 62;
                const int sx1 = (int)((ti >> 15) & 255u) - 64;
                const int sy1 = (int)((ti >> 23) & 127u) - 62;
                #pragma unroll
                for (int cn = 0; cn < 4; ++cn) {
                    const float wgt = h2f((unsigned short)(tw >> (16 * cn)));
                    if (wgt == 0.f) continue;
                    const int sx = (cn & 1) ? sx1 : sx0;
                    const int sy = (cn & 2) ? sy1 : sy0;
                    u32x4 v;
                    if (((unsigned)sx <= 39u) & ((unsigned)sy <= 4u))
                        v = wb[sy * PADX + sx];
                    else
                        v = plane4[(size_t)((y - 2 + sy) * W + (xb - 4 + sx)) * 2 + half];
                    #pragma unroll
                    for (int e = 0; e < 4; ++e) {
                        acc[2 * e]     = fmaf(wgt, __uint_as_float(v[e] << 16), acc[2 * e]);
                        acc[2 * e + 1] = fmaf(wgt, __uint_as_float(v[e] & 0xffff0000u), acc[2 * e + 1]);
                    }
                }
            }
            // write 8 ch (16B) -> smp swizzled
            bf16x8 pk;
            #pragma unroll
            for (int e = 0; e < 8; ++e) pk[e] = f2bf(acc[e]);
            *(bf16x8*)((char*)smp + spx * 256 + ((g * 32 + half * 16) ^ swz)) = pk;
        }
    }
    __syncthreads();

    // ---- output projection via MFMA (nt-partitioned) ----
    {
        const int w = t >> 6, l = t & 63;
        const int swA = (l & 7) << 4;
        bf16x8 aS[2][4];
        #pragma unroll
        for (int mt = 0; mt < 2; ++mt) {
            const int m = mt * 16 + (l & 15);
            #pragma unroll
            for (int kt = 0; kt < 4; ++kt)
                aS[mt][kt] = *(const bf16x8*)((char*)smp + m * 256 +
                                              ((kt * 64 + (l >> 4) * 16) ^ swA));
        }
        #pragma unroll
        for (int i = 0; i < 2; ++i) {
            const int nt = w + i * 4;
            bf16x8 bf[4];
            const short* bp = pk_out + nt * 2048 + l * 8;
            #pragma unroll
            for (int kt = 0; kt < 4; ++kt) bf[kt] = *(const bf16x8*)(bp + kt * 512);
            const float bias = b_out[nt * 16 + (l & 15)];
            #pragma unroll
            for (int mt = 0; mt < 2; ++mt) {
                f32x4 acc = {0.f, 0.f, 0.f, 0.f};
                #pragma unroll
                for (int kt = 0; kt < 4; ++kt)
                    acc = __builtin_amdgcn_mfma_f32_16x16x32_bf16(aS[mt][kt], bf[kt], acc, 0, 0, 0);
                const int row0 = gpix0 + mt * 16 + (l >> 4) * 4;
                #pragma unroll
                for (int r = 0; r < 4; ++r)
                    out[(size_t)(row0 + r) * C + nt * 16 + (l & 15)] = acc[r] + bias;
            }
        }
    }
}

extern "C" void kernel_launch(void* const* d_in, const int* in_sizes, int n_in,
                              void* d_out, int out_size, void* d_ws, size_t ws_size,
                              hipStream_t stream)
{
    const float* x     = (const float*)d_in[0];
    const float* w_in  = (const float*)d_in[1];
    const float* b_in  = (const float*)d_in[2];
    const float* dw_w  = (const float*)d_in[3];
    const float* dw_b  = (const float*)d_in[4];
    const float* ln_g  = (const float*)d_in[5];
    const float* ln_b  = (const float*)d_in[6];
    const float* w_off = (const float*)d_in[7];
    const float* b_off = (const float*)d_in[8];
    const float* w_msk = (const float*)d_in[9];
    const float* b_msk = (const float*)d_in[10];
    const float* w_out = (const float*)d_in[11];
    const float* b_out = (const float*)d_in[12];

    short* pk_in   = (short*)d_ws;
    short* pk_comb = pk_in + PK_IN_ELEMS;
    short* pk_out  = pk_comb + PK_COMB_ELEMS;
    unsigned short* xproj = (unsigned short*)(pk_out + PK_OUT_ELEMS);  // 8.4 MB planar bf16
    float* out     = (float*)d_out;

    hipLaunchKernelGGL(k_pack, dim3(240), dim3(256), 0, stream,
                       w_in, w_off, w_msk, w_out, pk_in, pk_comb, pk_out);
    hipLaunchKernelGGL(k_fm, dim3(NPIX / PXB), dim3(256), 0, stream,
                       x, dw_w, dw_b, ln_g, ln_b, pk_in, b_in,
                       pk_comb, b_off, b_msk, xproj, out);
    hipLaunchKernelGGL(k_samp, dim3(NPIX / PXB), dim3(256), 0, stream,
                       xproj, pk_out, b_out, out);
}